// Round 11
// baseline (170.730 us; speedup 1.0000x reference)
//
#include <hip/hip_runtime.h>
#include <hip/hip_bf16.h>
#include <cfloat>

#define NPTS 16384
#define NTILES 512          // 32-point tiles per side
#define R 4                 // A-tiles per wave; block of 4 waves = 16 A-tiles
#define BS 16               // B-chunk splits
#define CPT (NTILES / BS)   // 32 B-tiles per chunk
#define GRP 8               // B-tiles staged per group (8 KB), double-buffered

typedef short short8  __attribute__((ext_vector_type(8)));
typedef float f32x16  __attribute__((ext_vector_type(16)));

__device__ inline short bf16s(float x) {
    __hip_bfloat16 h = __float2bfloat16(x);   // RNE
    return *reinterpret_cast<short*>(&h);
}
__device__ inline float bf16f(short s) {
    __hip_bfloat16 h = *reinterpret_cast<__hip_bfloat16*>(&s);
    return __bfloat162float(h);
}

// Build per-tile MFMA fragments (identical to R9 — verified absmax 0).
// Slot map s = 8*(lane>>5) + j, j in [0,8).
// A row s-values:  [ahx ahy ahz alx aly alz ahx ahy | ahz 1 1 sqa_hi sqa_lo 0 0 0]
// B col s-values:  [bhx bhy bhz bhx bhy bhz blx bly | blz sqb_hi sqb_lo 1 1 0 0 0]
// Sum over s = -2 a.b + |b|^2 + |a|^2 = d^2 (missing only -2*alo*blo ~ 5e-5).
__global__ __launch_bounds__(256) void pack_kernel(
    const float* __restrict__ target, const float* __restrict__ output,
    short8* __restrict__ afrag, short8* __restrict__ bfrag)
{
    int t = blockIdx.x * 256 + threadIdx.x;   // [0, 2*512*64)
    int lane = t & 63;
    int tile = (t >> 6) & (NTILES - 1);
    int dir  = t >> 15;
    const float* __restrict__ A = dir ? target : output;  // query side
    const float* __restrict__ B = dir ? output : target;  // candidate side
    int p = tile * 32 + (lane & 31);
    int g = lane >> 5;
    int idx = (dir * NTILES + tile) * 64 + lane;

    {
        float x = A[3 * p], y = A[3 * p + 1], z = A[3 * p + 2];
        short hx = bf16s(x), hy = bf16s(y), hz = bf16s(z);
        short lx = bf16s(x - bf16f(hx)), ly = bf16s(y - bf16f(hy)), lz = bf16s(z - bf16f(hz));
        float sq = fmaf(x, x, fmaf(y, y, z * z));
        short sh = bf16s(sq), sl = bf16s(sq - bf16f(sh));
        const short one = 0x3F80;
        short8 loa = { hx, hy, hz, lx, ly, lz, hx, hy };
        short8 hia = { hz, one, one, sh, sl, 0, 0, 0 };
        afrag[idx] = g ? hia : loa;
    }
    {
        float x = B[3 * p], y = B[3 * p + 1], z = B[3 * p + 2];
        float nx = -2.f * x, ny = -2.f * y, nz = -2.f * z;
        short hx = bf16s(nx), hy = bf16s(ny), hz = bf16s(nz);
        short lx = bf16s(nx - bf16f(hx)), ly = bf16s(ny - bf16f(hy)), lz = bf16s(nz - bf16f(hz));
        float sq = fmaf(x, x, fmaf(y, y, z * z));
        short sh = bf16s(sq), sl = bf16s(sq - bf16f(sh));
        const short one = 0x3F80;
        short8 lob = { hx, hy, hz, hx, hy, hz, lx, ly };
        short8 hib = { lz, sh, sl, one, one, 0, 0, 0 };
        bfrag[idx] = g ? hib : lob;
    }
}

// Block = 4 waves sharing B tiles via double-buffered LDS.
// Wave w owns A-tiles ag*16 + w*4 + r; block sweeps a 32-tile B chunk.
// C/D layout (m74/m101): col=lane&31, row=(reg&3)+8*(reg>>2)+4*(lane>>5).
__global__ __launch_bounds__(256) void chamfer_mfma_kernel(
    const short8* __restrict__ afrag, const short8* __restrict__ bfrag,
    int* __restrict__ minsq)
{
    __shared__ short8 bsm[2][GRP * 64];   // 2 x 8 KB

    const int lane = threadIdx.x & 63;
    const int w    = threadIdx.x >> 6;
    const int bid  = blockIdx.x;          // [0, 1024)
    const int dir  = bid >> 9;
    const int rem  = bid & 511;
    const int ag   = rem >> 4;            // A-group [0,32)
    const int bc   = rem & 15;            // B-chunk [0,16)

    const short8* __restrict__ af = afrag + (size_t)dir * NTILES * 64;
    // contiguous fragment stream for this chunk: gsrc[f], f in [0, CPT*64)
    const short8* __restrict__ gsrc = bfrag + (size_t)dir * NTILES * 64
                                            + (size_t)(bc * CPT) * 64;

    short8 a[R];
    #pragma unroll
    for (int r = 0; r < R; ++r)
        a[r] = af[(ag * 16 + w * R + r) * 64 + lane];

    f32x16 m[R];
    #pragma unroll
    for (int r = 0; r < R; ++r)
        m[r] = (f32x16)(FLT_MAX);

    // prologue: stage group 0
    bsm[0][threadIdx.x]       = gsrc[threadIdx.x];
    bsm[0][threadIdx.x + 256] = gsrc[threadIdx.x + 256];
    __syncthreads();

    const f32x16 zero = (f32x16)(0.0f);
    #pragma unroll
    for (int grp = 0; grp < CPT / GRP; ++grp) {     // 4 groups
        const int cur = grp & 1;
        // issue next group's global loads early — hidden under this group's compute
        short8 n0, n1;
        if (grp < CPT / GRP - 1) {
            n0 = gsrc[(grp + 1) * (GRP * 64) + threadIdx.x];
            n1 = gsrc[(grp + 1) * (GRP * 64) + 256 + threadIdx.x];
        }
        // compute 8 tiles from bsm[cur]
        #pragma unroll
        for (int t = 0; t < GRP; t += 2) {
            short8 bb0 = bsm[cur][t * 64 + lane];
            short8 bb1 = bsm[cur][(t + 1) * 64 + lane];
            #pragma unroll
            for (int r = 0; r < R; ++r) {
                f32x16 c0 = __builtin_amdgcn_mfma_f32_32x32x16_bf16(a[r], bb0, zero, 0, 0, 0);
                f32x16 c1 = __builtin_amdgcn_mfma_f32_32x32x16_bf16(a[r], bb1, zero, 0, 0, 0);
                #pragma unroll
                for (int i = 0; i < 16; ++i)
                    m[r][i] = fminf(m[r][i], fminf(c0[i], c1[i]));   // v_min3_f32
            }
        }
        // write next group into the other buffer (safe: prev group's barrier
        // guarantees everyone is done reading it), then one barrier per group
        if (grp < CPT / GRP - 1) {
            bsm[cur ^ 1][threadIdx.x]       = n0;
            bsm[cur ^ 1][threadIdx.x + 256] = n1;
        }
        __syncthreads();
    }

    // butterfly min over the 32 cols (xor bits 0..4 stay within each 32-half)
    #pragma unroll
    for (int r = 0; r < R; ++r) {
        #pragma unroll
        for (int i = 0; i < 16; ++i) {
            float v = m[r][i];
            v = fminf(v, __shfl_xor(v, 1, 64));
            v = fminf(v, __shfl_xor(v, 2, 64));
            v = fminf(v, __shfl_xor(v, 4, 64));
            v = fminf(v, __shfl_xor(v, 8, 64));
            v = fminf(v, __shfl_xor(v, 16, 64));
            m[r][i] = v;
        }
    }

    // one lane per 32-half publishes its 16 row-mins (signed-int float order)
    if ((lane & 31) == 0) {
        const int g = lane >> 5;
        #pragma unroll
        for (int r = 0; r < R; ++r) {
            const int at = ag * 16 + w * R + r;
            #pragma unroll
            for (int i = 0; i < 16; ++i) {
                int row = (i & 3) + 8 * (i >> 2) + 4 * g;
                atomicMin(&minsq[dir * NPTS + at * 32 + row], __float_as_int(m[r][i]));
            }
        }
    }
}

__global__ __launch_bounds__(256) void reduce_kernel(
    const int* __restrict__ minsq, float* __restrict__ out)
{
    float s = 0.f;
    const int4* mv = (const int4*)minsq;   // 2*NPTS/4 = 8192 int4s
    for (int k = blockIdx.x * 256 + threadIdx.x; k < 2 * NPTS / 4; k += gridDim.x * 256) {
        int4 v = mv[k];
        s += sqrtf(fmaxf(__int_as_float(v.x), 0.f))
           + sqrtf(fmaxf(__int_as_float(v.y), 0.f))
           + sqrtf(fmaxf(__int_as_float(v.z), 0.f))
           + sqrtf(fmaxf(__int_as_float(v.w), 0.f));
    }
    for (int off = 32; off; off >>= 1) s += __shfl_down(s, off, 64);
    __shared__ float partial[4];
    if ((threadIdx.x & 63) == 0) partial[threadIdx.x >> 6] = s;
    __syncthreads();
    if (threadIdx.x == 0)
        atomicAdd(out, (partial[0] + partial[1] + partial[2] + partial[3]) * 0.001f);
}

extern "C" void kernel_launch(void* const* d_in, const int* in_sizes, int n_in,
                              void* d_out, int out_size, void* d_ws, size_t ws_size,
                              hipStream_t stream) {
    const float* target = (const float*)d_in[0];  // [16384,3]
    const float* output = (const float*)d_in[1];  // [16384,3]
    float* out = (float*)d_out;

    // ws: afrag 1MB | bfrag 1MB | minsq 128KB
    short8* afrag = (short8*)d_ws;
    short8* bfrag = afrag + 2 * NTILES * 64;
    int* minsq = (int*)(bfrag + 2 * NTILES * 64);

    hipMemsetAsync(minsq, 0x7F, 2 * NPTS * sizeof(int), stream);
    hipMemsetAsync(out, 0, sizeof(float), stream);

    pack_kernel<<<2 * NTILES * 64 / 256, 256, 0, stream>>>(target, output, afrag, bfrag);
    chamfer_mfma_kernel<<<2 * 32 * BS, 256, 0, stream>>>(afrag, bfrag, minsq);
    reduce_kernel<<<32, 256, 0, stream>>>(minsq, out);
}

// Round 12
// 86.657 us; speedup vs baseline: 1.9702x; 1.9702x over previous
//
#include <hip/hip_runtime.h>
#include <hip/hip_bf16.h>
#include <cfloat>

#define NPTS 16384
#define NTILES 512          // 32-point tiles per side
#define R 2                 // A-tiles per wave (small => small acc footprint)
#define BS 8                // B-chunk splits
#define CPT (NTILES / BS)   // 64 B-tiles per chunk

typedef short short8  __attribute__((ext_vector_type(8)));
typedef float f32x16  __attribute__((ext_vector_type(16)));

__device__ inline short bf16s(float x) {
    __hip_bfloat16 h = __float2bfloat16(x);   // RNE
    return *reinterpret_cast<short*>(&h);
}
__device__ inline float bf16f(short s) {
    __hip_bfloat16 h = *reinterpret_cast<__hip_bfloat16*>(&s);
    return __bfloat162float(h);
}

// Build per-tile MFMA fragments (identical to R9 — verified absmax 0).
// Slot map s = 8*(lane>>5) + j, j in [0,8).
// A row s-values:  [ahx ahy ahz alx aly alz ahx ahy | ahz 1 1 sqa_hi sqa_lo 0 0 0]
// B col s-values:  [bhx bhy bhz bhx bhy bhz blx bly | blz sqb_hi sqb_lo 1 1 0 0 0]
// Sum over s = -2 a.b + |b|^2 + |a|^2 = d^2 (missing only -2*alo*blo ~ 5e-5).
__global__ __launch_bounds__(256) void pack_kernel(
    const float* __restrict__ target, const float* __restrict__ output,
    short8* __restrict__ afrag, short8* __restrict__ bfrag)
{
    int t = blockIdx.x * 256 + threadIdx.x;   // [0, 2*512*64)
    int lane = t & 63;
    int tile = (t >> 6) & (NTILES - 1);
    int dir  = t >> 15;
    const float* __restrict__ A = dir ? target : output;  // query side
    const float* __restrict__ B = dir ? output : target;  // candidate side
    int p = tile * 32 + (lane & 31);
    int g = lane >> 5;
    int idx = (dir * NTILES + tile) * 64 + lane;

    {
        float x = A[3 * p], y = A[3 * p + 1], z = A[3 * p + 2];
        short hx = bf16s(x), hy = bf16s(y), hz = bf16s(z);
        short lx = bf16s(x - bf16f(hx)), ly = bf16s(y - bf16f(hy)), lz = bf16s(z - bf16f(hz));
        float sq = fmaf(x, x, fmaf(y, y, z * z));
        short sh = bf16s(sq), sl = bf16s(sq - bf16f(sh));
        const short one = 0x3F80;
        short8 loa = { hx, hy, hz, lx, ly, lz, hx, hy };
        short8 hia = { hz, one, one, sh, sl, 0, 0, 0 };
        afrag[idx] = g ? hia : loa;
    }
    {
        float x = B[3 * p], y = B[3 * p + 1], z = B[3 * p + 2];
        float nx = -2.f * x, ny = -2.f * y, nz = -2.f * z;
        short hx = bf16s(nx), hy = bf16s(ny), hz = bf16s(nz);
        short lx = bf16s(nx - bf16f(hx)), ly = bf16s(ny - bf16f(hy)), lz = bf16s(nz - bf16f(hz));
        float sq = fmaf(x, x, fmaf(y, y, z * z));
        short sh = bf16s(sq), sl = bf16s(sq - bf16f(sh));
        const short one = 0x3F80;
        short8 lob = { hx, hy, hz, hx, hy, hz, lx, ly };
        short8 hib = { lz, sh, sl, one, one, 0, 0, 0 };
        bfrag[idx] = g ? hib : lob;
    }
}

// Each wave: R=2 fixed A-tiles (arg0) vs a 64-tile B chunk (arg1), fence-free.
// Small accumulator footprint (2 x f32x16) -> 4 waves/SIMD resident.
// C/D layout (m74/m101): col=lane&31, row=(reg&3)+8*(reg>>2)+4*(lane>>5).
__global__ __launch_bounds__(256, 4) void chamfer_mfma_kernel(
    const short8* __restrict__ afrag, const short8* __restrict__ bfrag,
    int* __restrict__ minsq)
{
    const int lane = threadIdx.x & 63;
    const int wid  = blockIdx.x * 4 + (threadIdx.x >> 6);  // [0,4096)
    const int dir  = wid >> 11;
    const int rem  = wid & 2047;
    const int ag   = rem >> 3;    // A-group [0,256)
    const int bc   = rem & 7;     // B-chunk [0,8)

    const short8* __restrict__ af = afrag + (size_t)dir * NTILES * 64;
    const short8* __restrict__ gsrc = bfrag + (size_t)dir * NTILES * 64
                                            + (size_t)(bc * CPT) * 64;

    short8 a[R];
    #pragma unroll
    for (int r = 0; r < R; ++r)
        a[r] = af[(ag * R + r) * 64 + lane];

    f32x16 m[R];
    #pragma unroll
    for (int r = 0; r < R; ++r)
        m[r] = (f32x16)(FLT_MAX);

    const f32x16 zero = (f32x16)(0.0f);
    for (int pp = 0; pp < CPT / 2; ++pp) {
        short8 b0 = gsrc[(2 * pp + 0) * 64 + lane];
        short8 b1 = gsrc[(2 * pp + 1) * 64 + lane];
        #pragma unroll
        for (int r = 0; r < R; ++r) {
            f32x16 c0 = __builtin_amdgcn_mfma_f32_32x32x16_bf16(a[r], b0, zero, 0, 0, 0);
            f32x16 c1 = __builtin_amdgcn_mfma_f32_32x32x16_bf16(a[r], b1, zero, 0, 0, 0);
            #pragma unroll
            for (int i = 0; i < 16; ++i)
                m[r][i] = fminf(m[r][i], fminf(c0[i], c1[i]));   // v_min3_f32
        }
    }

    // butterfly min over the 32 cols (xor bits 0..4 stay within each 32-half)
    #pragma unroll
    for (int r = 0; r < R; ++r) {
        #pragma unroll
        for (int i = 0; i < 16; ++i) {
            float v = m[r][i];
            v = fminf(v, __shfl_xor(v, 1, 64));
            v = fminf(v, __shfl_xor(v, 2, 64));
            v = fminf(v, __shfl_xor(v, 4, 64));
            v = fminf(v, __shfl_xor(v, 8, 64));
            v = fminf(v, __shfl_xor(v, 16, 64));
            m[r][i] = v;
        }
    }

    // one lane per 32-half publishes its 16 row-mins (signed-int float order;
    // tiny-negative d^2 maps to large-negative int -> wins min -> clamped later)
    if ((lane & 31) == 0) {
        const int g = lane >> 5;
        #pragma unroll
        for (int r = 0; r < R; ++r) {
            const int at = ag * R + r;
            #pragma unroll
            for (int i = 0; i < 16; ++i) {
                int row = (i & 3) + 8 * (i >> 2) + 4 * g;
                atomicMin(&minsq[dir * NPTS + at * 32 + row], __float_as_int(m[r][i]));
            }
        }
    }
}

__global__ __launch_bounds__(256) void reduce_kernel(
    const int* __restrict__ minsq, float* __restrict__ out)
{
    float s = 0.f;
    const int4* mv = (const int4*)minsq;   // 2*NPTS/4 = 8192 int4s
    for (int k = blockIdx.x * 256 + threadIdx.x; k < 2 * NPTS / 4; k += gridDim.x * 256) {
        int4 v = mv[k];
        s += sqrtf(fmaxf(__int_as_float(v.x), 0.f))
           + sqrtf(fmaxf(__int_as_float(v.y), 0.f))
           + sqrtf(fmaxf(__int_as_float(v.z), 0.f))
           + sqrtf(fmaxf(__int_as_float(v.w), 0.f));
    }
    for (int off = 32; off; off >>= 1) s += __shfl_down(s, off, 64);
    __shared__ float partial[4];
    if ((threadIdx.x & 63) == 0) partial[threadIdx.x >> 6] = s;
    __syncthreads();
    if (threadIdx.x == 0)
        atomicAdd(out, (partial[0] + partial[1] + partial[2] + partial[3]) * 0.001f);
}

extern "C" void kernel_launch(void* const* d_in, const int* in_sizes, int n_in,
                              void* d_out, int out_size, void* d_ws, size_t ws_size,
                              hipStream_t stream) {
    const float* target = (const float*)d_in[0];  // [16384,3]
    const float* output = (const float*)d_in[1];  // [16384,3]
    float* out = (float*)d_out;

    // ws: afrag 1MB | bfrag 1MB | minsq 128KB
    short8* afrag = (short8*)d_ws;
    short8* bfrag = afrag + 2 * NTILES * 64;
    int* minsq = (int*)(bfrag + 2 * NTILES * 64);

    hipMemsetAsync(minsq, 0x7F, 2 * NPTS * sizeof(int), stream);
    hipMemsetAsync(out, 0, sizeof(float), stream);

    pack_kernel<<<2 * NTILES * 64 / 256, 256, 0, stream>>>(target, output, afrag, bfrag);
    // waves = 2 dirs * 256 ag * 8 bc = 4096 -> 1024 blocks -> 4 blocks/CU
    chamfer_mfma_kernel<<<1024, 256, 0, stream>>>(afrag, bfrag, minsq);
    reduce_kernel<<<32, 256, 0, stream>>>(minsq, out);
}